// Round 7
// baseline (194.062 us; speedup 1.0000x reference)
//
#include <hip/hip_runtime.h>

#define BATCH 4
#define SEQ   4096
#define DIM   1024
#define EPS_F 1e-6f
#define KSPLIT 4

typedef __bf16 bf16_t;
typedef bf16_t bf16x8 __attribute__((ext_vector_type(8)));
typedef float  f32x4  __attribute__((ext_vector_type(4)));
typedef unsigned short u16x8 __attribute__((ext_vector_type(8)));

__device__ __forceinline__ unsigned short f2bf(float f) {
  unsigned u = __float_as_uint(f);
  u += 0x7FFFu + ((u >> 16) & 1u);          // round-to-nearest-even
  return (unsigned short)(u >> 16);
}
__device__ __forceinline__ float bf2f(unsigned short h) {
  return __uint_as_float(((unsigned)h) << 16);
}
__device__ __forceinline__ float phi_f(float x) {
  return x > 0.f ? x + 1.f : __expf(x);     // elu(x)+1
}

__global__ __launch_bounds__(256) void zero_f32(float* __restrict__ p, int n) {
  const int i = blockIdx.x * 256 + threadIdx.x;
  if (i < n) p[i] = 0.f;
}

// ---- transpose (+ optional phi, optional fused column-sum) ----
template<bool PHI, bool KSUM>
__global__ __launch_bounds__(256) void phi_transpose(const float* __restrict__ in,
    unsigned short* __restrict__ out, float* __restrict__ ksum, int rows, int cols) {
  __shared__ float t[32][33];
  __shared__ float ps[8][32];
  const int bx = blockIdx.x * 32;          // col base
  const int by = blockIdx.y * 32;          // row base
  const size_t bo = (size_t)blockIdx.z * rows * cols;
  const int x = threadIdx.x, y = threadIdx.y;
  #pragma unroll
  for (int j = 0; j < 32; j += 8) {
    float v = in[bo + (size_t)(by + y + j) * cols + bx + x];
    if (PHI) v = phi_f(v);
    t[y + j][x] = v;
  }
  __syncthreads();
  #pragma unroll
  for (int j = 0; j < 32; j += 8)
    out[bo + (size_t)(bx + y + j) * rows + by + x] = f2bf(t[x][y + j]);
  if (KSUM) {
    float s = t[y][x] + t[y + 8][x] + t[y + 16][x] + t[y + 24][x];
    ps[y][x] = s;
    __syncthreads();
    if (y == 0) {
      float tot = 0.f;
      #pragma unroll
      for (int j = 0; j < 8; ++j) tot += ps[j][x];
      atomicAdd(&ksum[(size_t)blockIdx.z * cols + bx + x], tot);
    }
  }
}

// ---- phi(Q) cast + fused Z ----
__global__ __launch_bounds__(256) void phi_cast_qz(const float* __restrict__ Q,
    const float* __restrict__ Ksum, unsigned short* __restrict__ Qp,
    float* __restrict__ invZ) {
  const int row  = blockIdx.x * 4 + (threadIdx.x >> 6);   // b*SEQ + n
  const int lane = threadIdx.x & 63;
  const int b = row >> 12;
  const float* q  = Q + (size_t)row * DIM;
  const float* ks = Ksum + (size_t)b * DIM;
  float s = 0.f;
  #pragma unroll
  for (int c = 0; c < 2; ++c) {
    const int d0 = c * 512 + lane * 8;
    float4 v0 = *(const float4*)(q + d0);
    float4 v1 = *(const float4*)(q + d0 + 4);
    float4 k0 = *(const float4*)(ks + d0);
    float4 k1 = *(const float4*)(ks + d0 + 4);
    u16x8 o;
    o[0] = f2bf(phi_f(v0.x)); s += bf2f(o[0]) * k0.x;
    o[1] = f2bf(phi_f(v0.y)); s += bf2f(o[1]) * k0.y;
    o[2] = f2bf(phi_f(v0.z)); s += bf2f(o[2]) * k0.z;
    o[3] = f2bf(phi_f(v0.w)); s += bf2f(o[3]) * k0.w;
    o[4] = f2bf(phi_f(v1.x)); s += bf2f(o[4]) * k1.x;
    o[5] = f2bf(phi_f(v1.y)); s += bf2f(o[5]) * k1.y;
    o[6] = f2bf(phi_f(v1.z)); s += bf2f(o[6]) * k1.z;
    o[7] = f2bf(phi_f(v1.w)); s += bf2f(o[7]) * k1.w;
    *(u16x8*)(Qp + (size_t)row * DIM + d0) = o;
  }
  #pragma unroll
  for (int off = 32; off > 0; off >>= 1) s += __shfl_down(s, off);
  if (lane == 0) invZ[row] = 1.0f / (s + EPS_F);
}

// ---- reduce KSPLIT bf16 partials -> bf16 KVt ----
__global__ __launch_bounds__(256) void reduce_kv(const unsigned short* __restrict__ P,
    unsigned short* __restrict__ KVt) {
  const size_t per = (size_t)DIM * DIM;
  const size_t i = ((size_t)blockIdx.x * 256 + threadIdx.x) * 8;
  const size_t b = blockIdx.y;
  const unsigned short* p = P + b * KSPLIT * per + i;
  float s[8] = {};
  #pragma unroll
  for (int sp = 0; sp < KSPLIT; ++sp) {
    u16x8 v = *(const u16x8*)(p + sp * per);
    #pragma unroll
    for (int j = 0; j < 8; ++j) s[j] += bf2f(v[j]);
  }
  u16x8 o;
  #pragma unroll
  for (int j = 0; j < 8; ++j) o[j] = f2bf(s[j]);
  *(u16x8*)(KVt + b * per + i) = o;
}

// ========== 256x256 bt-GEMM: A via LDS (dbuf), B direct-from-global ==========
// C[M][Nc] = A[M][K] * Bm[Nc][K]^T. 512 thr = 8 waves (2M x 4N), BK=64.
// One barrier per K-tile. B-fragments prefetched one K-tile ahead into
// ping-ponged register sets (B slab is L2-resident: KVt 2MB / Kt-slab 2MB,
// XCD-swizzle co-locates sharers). vmcnt FIFO: per tile issue A-stage(4) then
// B-loads(8); head vmcnt(8)=A landed; pre-MFMA vmcnt(12)=prev B landed.
#define GLD(gp, lp) __builtin_amdgcn_global_load_lds( \
    (const __attribute__((address_space(1))) unsigned int*)(gp), \
    (__attribute__((address_space(3))) unsigned int*)(lp), 16, 0, 0)
#define BARRIER __builtin_amdgcn_s_barrier()
#define WAITV(n) asm volatile("s_waitcnt vmcnt(" #n ")" ::: "memory")

template<int EPI, int KS, int NT>
__global__ __launch_bounds__(512, 1) void gemm256g(
    const unsigned short* __restrict__ A, const unsigned short* __restrict__ Bm,
    void* __restrict__ Cv, const float* __restrict__ invZ,
    int M, int Nc, int K, int gx, int gy) {
  __shared__ unsigned short As0[16384];   // 32 KB: 256 rows x 64 k
  __shared__ unsigned short As1[16384];

  const int t    = threadIdx.x;
  const int wid  = t >> 6;
  const int lane = t & 63;
  // XCD-chunked bijective swizzle (gridDim.x divisible by 8)
  const int id   = blockIdx.x;
  const int sw   = (id & 7) * (gridDim.x >> 3) + (id >> 3);
  const int bxi  = sw % gx;
  const int rem  = sw / gx;
  const int byi  = rem % gy;
  const int bz   = rem / gy;
  const int brow = byi * 256, bcol = bxi * 256;
  const size_t batch = bz / KS;
  const int split = bz % KS;
  const int Kc = K / KS;
  const unsigned short* Ab = A + batch * ((size_t)M * K) + (size_t)brow * K + (size_t)split * Kc;
  const unsigned short* Bb = Bm + batch * ((size_t)Nc * K) + (size_t)bcol * K + (size_t)split * Kc;

  // A staging: thread t -> row t>>3 (+i*64), chunk t&7 linear in LDS; global
  // chunk pre-swizzled with row&7 (read side applies same XOR).
  const int srow_t = t >> 3;
  const int c_src  = (t & 7) ^ (srow_t & 7);
  const unsigned short* gA = Ab + (size_t)srow_t * K + c_src * 8;
  const int ldsAu = wid * 512;             // wave-uniform LDS elem base

  auto stageA = [&](unsigned short* D, int kt) {
    #pragma unroll
    for (int i2 = 0; i2 < 4; ++i2)
      GLD(gA + (size_t)(i2 * 64) * K + (size_t)kt * 64, D + (i2 * 64) * 64 + ldsAu);
  };

  const int fr  = lane & 15;
  const int g   = lane >> 4;
  const int wrw = (wid >> 2) * 128;          // wave row base (2 M-groups)
  const int wcw = (wid & 3) * 64;            // wave col base (4 N-groups)
  const int ck0 = ((g)     ^ (fr & 7)) * 8;  // kk=0 swizzled chunk (elems)
  const int ck1 = ((4 + g) ^ (fr & 7)) * 8;  // kk=1

  // per-lane B fragment row bases (B[col][k], 16B aligned)
  const unsigned short* rb[2][2];
  #pragma unroll
  for (int nh = 0; nh < 2; ++nh)
    #pragma unroll
    for (int n2 = 0; n2 < 2; ++n2)
      rb[nh][n2] = Bb + (size_t)(wcw + nh * 32 + n2 * 16 + fr) * K + g * 8;

  f32x4 acc[8][4] = {};
  bf16x8 af[4][2], bfA[2][2][2], bfB[2][2][2];

#define LOADA_(S, mh) { _Pragma("unroll") for (int m_ = 0; m_ < 4; ++m_) { \
    const int ro_ = (wrw + ((mh) * 4 + m_) * 16 + fr) * 64; \
    af[m_][0] = *(const bf16x8*)((S) + ro_ + ck0); \
    af[m_][1] = *(const bf16x8*)((S) + ro_ + ck1); } }
#define ISSUEB_(DST, ktv) { _Pragma("unroll") for (int nh_ = 0; nh_ < 2; ++nh_) \
    _Pragma("unroll") for (int n2_ = 0; n2_ < 2; ++n2_) \
    _Pragma("unroll") for (int kk_ = 0; kk_ < 2; ++kk_) \
      DST[nh_][n2_][kk_] = *(const bf16x8*)(rb[nh_][n2_] + (size_t)(ktv) * 64 + kk_ * 32); }
#define QUADX_(mh, nh, BF) { __builtin_amdgcn_s_setprio(1); \
    _Pragma("unroll") for (int m_ = 0; m_ < 4; ++m_) \
    _Pragma("unroll") for (int n_ = 0; n_ < 2; ++n_) \
    _Pragma("unroll") for (int k_ = 0; k_ < 2; ++k_) \
      acc[(mh) * 4 + m_][(nh) * 2 + n_] = __builtin_amdgcn_mfma_f32_16x16x32_bf16( \
          af[m_][k_], BF[nh][n_][k_], acc[(mh) * 4 + m_][(nh) * 2 + n_], 0, 0, 0); \
    __builtin_amdgcn_s_setprio(0); }
// Tile t: head vmcnt(8)+barrier (A(t) landed everywhere; all reads of SN done
// last tile so staging into it is safe); ds_read A half0; stage A(t+1); issue
// B(t+1); vmcnt(12) (=4+8 just issued -> B(t) landed); 2 quads; half1; 2 quads.
#define TILE_FULL(CUR, NXT, SP, SN) { \
    WAITV(8); BARRIER; \
    LOADA_(SP, 0); \
    stageA(SN, kt + 1); \
    ISSUEB_(NXT, kt + 1); \
    WAITV(12); \
    QUADX_(0, 0, CUR); QUADX_(0, 1, CUR); \
    LOADA_(SP, 1); \
    QUADX_(1, 0, CUR); QUADX_(1, 1, CUR); \
    ++kt; }

  int kt = 0;
  stageA(As0, 0);          // A(0): 4 gld_lds
  ISSUEB_(bfA, 0);         // B(0): 8 loads
  #pragma unroll 1
  for (int i = 0; i < NT / 2 - 1; ++i) {
    TILE_FULL(bfA, bfB, As0, As1);   // even tile
    TILE_FULL(bfB, bfA, As1, As0);   // odd tile
  }
  TILE_FULL(bfA, bfB, As0, As1);     // tile NT-2 (stages A(NT-1), issues B(NT-1))
  // last tile NT-1: reads As1, uses bfB; nothing left to prefetch
  WAITV(8); BARRIER;                 // A(NT-1) landed (8 = B(NT-1) in flight)
  LOADA_(As1, 0);
  WAITV(0);                          // B(NT-1) landed
  QUADX_(0, 0, bfB); QUADX_(0, 1, bfB);
  LOADA_(As1, 1);
  QUADX_(1, 0, bfB); QUADX_(1, 1, bfB);
#undef LOADA_
#undef ISSUEB_
#undef QUADX_
#undef TILE_FULL

  // epilogue: C/D layout col=fr, row=g*4+r per 16x16 fragment
  if (EPI == 0) {
    unsigned short* Cb = (unsigned short*)Cv + (size_t)bz * M * Nc;
    #pragma unroll
    for (int m = 0; m < 8; ++m) {
      const int row = brow + wrw + m * 16 + g * 4;
      #pragma unroll
      for (int r = 0; r < 4; ++r)
        #pragma unroll
        for (int n = 0; n < 4; ++n)
          Cb[(size_t)(row + r) * Nc + bcol + wcw + n * 16 + fr] = f2bf(acc[m][n][r]);
    }
  } else {
    float* Cb = (float*)Cv + batch * ((size_t)M * Nc);
    const float* zb = invZ + batch * (size_t)M;
    #pragma unroll
    for (int m = 0; m < 8; ++m) {
      const int row = brow + wrw + m * 16 + g * 4;
      #pragma unroll
      for (int r = 0; r < 4; ++r) {
        const float z = zb[row + r];
        #pragma unroll
        for (int n = 0; n < 4; ++n)
          Cb[(size_t)(row + r) * Nc + bcol + wcw + n * 16 + fr] = acc[m][n][r] * z;
      }
    }
  }
}

extern "C" void kernel_launch(void* const* d_in, const int* in_sizes, int n_in,
                              void* d_out, int out_size, void* d_ws, size_t ws_size,
                              hipStream_t stream) {
  const float* Q = (const float*)d_in[0];
  const float* K = (const float*)d_in[1];
  const float* V = (const float*)d_in[2];
  float* out = (float*)d_out;

  char* ws = (char*)d_ws;
  size_t off = 0;
  auto alloc = [&](size_t bytes) {
    void* p = ws + off;
    off += (bytes + 255) & ~(size_t)255;
    return p;
  };
  unsigned short* Qp   = (unsigned short*)alloc((size_t)BATCH * SEQ * DIM * 2);
  unsigned short* P    = Qp;  // split-K partials [B][KSPLIT][DIM*DIM] bf16 = 32 MB
  unsigned short* Kt   = (unsigned short*)alloc((size_t)BATCH * SEQ * DIM * 2);
  unsigned short* Vt   = (unsigned short*)alloc((size_t)BATCH * SEQ * DIM * 2);
  unsigned short* KVt  = (unsigned short*)alloc((size_t)BATCH * DIM * DIM * 2);
  float* Ksum = (float*)alloc((size_t)BATCH * DIM * 4);
  float* invZ = (float*)alloc((size_t)BATCH * SEQ * 4);

  const dim3 tb(32, 8);
  zero_f32<<<(BATCH * DIM + 255) / 256, 256, 0, stream>>>(Ksum, BATCH * DIM);
  phi_transpose<true, true ><<<dim3(DIM / 32, SEQ / 32, BATCH), tb, 0, stream>>>(K, Kt, Ksum, SEQ, DIM);
  phi_transpose<false, false><<<dim3(DIM / 32, SEQ / 32, BATCH), tb, 0, stream>>>(V, Vt, nullptr, SEQ, DIM);
  // gemm1 split-K: P[b][s] = Vt * Kt^T over n-split s   (M=Nc=1024, Kc=1024 -> NT=16)
  gemm256g<0, KSPLIT, 16><<<(DIM / 256) * (DIM / 256) * BATCH * KSPLIT, 512, 0, stream>>>(
      Vt, Kt, P, nullptr, DIM, DIM, SEQ, DIM / 256, DIM / 256);
  reduce_kv<<<dim3(DIM * DIM / (256 * 8), BATCH), 256, 0, stream>>>(P, KVt);
  // phi(Q) cast + fused Z (after reduce: overwrites P region)
  phi_cast_qz<<<BATCH * SEQ / 4, 256, 0, stream>>>(Q, Ksum, Qp, invZ);
  // gemm2: out = (Qp * KVt^T) * invZ   (M=4096, Nc=1024, K=1024 -> NT=16)
  gemm256g<1, 1, 16><<<(DIM / 256) * (SEQ / 256) * BATCH, 512, 0, stream>>>(
      Qp, KVt, out, invZ, SEQ, DIM, DIM, DIM / 256, SEQ / 256);
}